// Round 5
// baseline (324.687 us; speedup 1.0000x reference)
//
#include <hip/hip_runtime.h>

#define EPSF 1e-5f

// Kernel 1: one WAVE (64 lanes) per (b,n) pair; 4 pairs per 256-thread block.
// Identical to round 3 (kept byte-identical so the added dummy launch's delta
// is a clean measurement of this kernel's cold-stream duration).
__global__ __launch_bounds__(256) void star_pair_kernel(
    const float* __restrict__ heatmap,
    const float* __restrict__ gt,
    float* __restrict__ pair_out,
    int npairs)
{
    const int t = threadIdx.x;
    const int wave = t >> 6;
    const int lane = t & 63;
    const int pair = blockIdx.x * 4 + wave;
    if (pair >= npairs) return;

    const float* hp = heatmap + (size_t)pair * 4096;

    const float cgrid = 2.0f / 63.0f;
    const float xb = (float)((lane & 15) << 2);
    const float xf0 = fmaf(xb,          cgrid, -1.0f);
    const float xf1 = fmaf(xb + 1.0f,   cgrid, -1.0f);
    const float xf2 = fmaf(xb + 2.0f,   cgrid, -1.0f);
    const float xf3 = fmaf(xb + 3.0f,   cgrid, -1.0f);
    const int   yb  = lane >> 4;

    float s0 = 0.f, s1 = 0.f, s2 = 0.f, s3 = 0.f, s4 = 0.f, s5 = 0.f, s6 = 0.f;

    #pragma unroll
    for (int j = 0; j < 16; ++j) {
        const float4 v = reinterpret_cast<const float4*>(hp)[lane + (j << 6)];
        const float yf = fmaf((float)(yb + (j << 2)), cgrid, -1.0f);
        const float a0 = v.x, a1 = v.y, a2 = v.z, a3 = v.w;

        s0 += a0; s6 = fmaf(a0, a0, s6);
        s1 = fmaf(a0, xf0, s1); s2 = fmaf(a0, yf, s2);
        { const float ax = a0 * xf0; s3 = fmaf(ax, xf0, s3); s4 = fmaf(ax, yf, s4); }
        { const float ay = a0 * yf;  s5 = fmaf(ay, yf, s5); }

        s0 += a1; s6 = fmaf(a1, a1, s6);
        s1 = fmaf(a1, xf1, s1); s2 = fmaf(a1, yf, s2);
        { const float ax = a1 * xf1; s3 = fmaf(ax, xf1, s3); s4 = fmaf(ax, yf, s4); }
        { const float ay = a1 * yf;  s5 = fmaf(ay, yf, s5); }

        s0 += a2; s6 = fmaf(a2, a2, s6);
        s1 = fmaf(a2, xf2, s1); s2 = fmaf(a2, yf, s2);
        { const float ax = a2 * xf2; s3 = fmaf(ax, xf2, s3); s4 = fmaf(ax, yf, s4); }
        { const float ay = a2 * yf;  s5 = fmaf(ay, yf, s5); }

        s0 += a3; s6 = fmaf(a3, a3, s6);
        s1 = fmaf(a3, xf3, s1); s2 = fmaf(a3, yf, s2);
        { const float ax = a3 * xf3; s3 = fmaf(ax, xf3, s3); s4 = fmaf(ax, yf, s4); }
        { const float ay = a3 * yf;  s5 = fmaf(ay, yf, s5); }
    }

    #pragma unroll
    for (int off = 32; off >= 1; off >>= 1) {
        s0 += __shfl_down(s0, off);
        s1 += __shfl_down(s1, off);
        s2 += __shfl_down(s2, off);
        s3 += __shfl_down(s3, off);
        s4 += __shfl_down(s4, off);
        s5 += __shfl_down(s5, off);
        s6 += __shfl_down(s6, off);
    }

    if (lane == 0) {
        const float S = s0 > 1e-6f ? s0 : 1e-6f;
        const float inv = 1.0f / S;
        const float T  = s0 * inv;
        const float mx = s1 * inv;
        const float my = s2 * inv;
        const float Exx = s3 * inv;
        const float Exy = s4 * inv;
        const float Eyy = s5 * inv;
        const float V2raw = s6 * inv * inv;

        const float c2mT = 2.0f - T;
        float c00 = Exx - mx * mx * c2mT;
        float c01 = Exy - mx * my * c2mT;
        float c11 = Eyy - my * my * c2mT;
        const float V1 = T + EPSF;
        const float denom = V1 - (V2raw + EPSF) / V1;
        const float idn = 1.0f / denom;
        c00 *= idn; c01 *= idn; c11 *= idn;

        const float mmid = 0.5f * (c00 + c11);
        const float h = 0.5f * (c00 - c11);
        const float r = sqrtf(h * h + c01 * c01);
        const float l0 = mmid - r;
        const float l1 = mmid + r;
        float vx = h + r, vy = c01;
        const float nn = vx * vx + vy * vy;
        float cc, ssn;
        if (nn > 1e-30f) {
            const float rin = rsqrtf(nn);
            cc = vx * rin; ssn = vy * rin;
        } else {
            cc = 0.0f; ssn = 1.0f;
        }

        const float px = gt[2 * pair]     - mx;
        const float py = gt[2 * pair + 1] - my;
        const float r1 = cc * px + ssn * py;
        const float r0 = -ssn * px + cc * py;

        const float ssum = r0 * r0 / (l0 + EPSF) + r1 * r1 / (l1 + EPSF);
        const float esum = fabsf(l0) + fabsf(l1);
        pair_out[pair] = 0.5f * ssum + esum;
    }
}

// Kernel 2: reduce per-pair contributions -> scalar loss.
__global__ __launch_bounds__(1024) void star_reduce_kernel(
    const float* __restrict__ pair_out,
    float* __restrict__ out,
    int n, float inv_n)
{
    float s = 0.f;
    for (int i = threadIdx.x; i < n; i += 1024) s += pair_out[i];
    #pragma unroll
    for (int off = 32; off >= 1; off >>= 1) s += __shfl_down(s, off);
    __shared__ float red[16];
    const int wave = threadIdx.x >> 6;
    const int lane = threadIdx.x & 63;
    if (lane == 0) red[wave] = s;
    __syncthreads();
    if (threadIdx.x == 0) {
        float tot = 0.f;
        #pragma unroll
        for (int w = 0; w < 16; ++w) tot += red[w];
        out[0] = tot * inv_n;
    }
}

extern "C" void kernel_launch(void* const* d_in, const int* in_sizes, int n_in,
                              void* d_out, int out_size, void* d_ws, size_t ws_size,
                              hipStream_t stream) {
    const float* heatmap = (const float*)d_in[0];
    const float* gt      = (const float*)d_in[1];
    float* out = (float*)d_out;
    float* pair_out = (float*)d_ws;

    const int npairs = in_sizes[1] / 2;   // 128*98 = 12544
    const int nblocks = (npairs + 3) / 4; // 4 pairs (waves) per block

    // ---- DIAGNOSTIC dummy launch (same kernel, reads poisoned ws) ----
    // Measures the cold-stream duration of star_pair_kernel's structure:
    // dur_us(this round) - dur_us(round 3) ~= this launch's time.
    // Region at the START of ws: the 822 MB ascending poison-fill evicts
    // the beginning of ws from L3 by the time it finishes -> cold read.
    // Results (incl. NaNs) go to a dead ws slot; real outputs unaffected.
    {
        const size_t MB = 1024 * 1024 / sizeof(float); // floats per MB
        const size_t need = (size_t)(212) * MB * sizeof(float);
        if (ws_size >= need + (size_t)16 * 1024 * 1024) {
            const float* dummy_hm  = (const float*)d_ws + 1 * MB;      // 205.5 MB
            const float* dummy_gt  = (const float*)d_ws + 207 * MB;    // 100 KB
            float*       dummy_out = (float*)d_ws + 209 * MB;          // 50 KB
            star_pair_kernel<<<nblocks, 256, 0, stream>>>(dummy_hm, dummy_gt,
                                                          dummy_out, npairs);
        }
    }
    // ------------------------------------------------------------------

    star_pair_kernel<<<nblocks, 256, 0, stream>>>(heatmap, gt, pair_out, npairs);
    star_reduce_kernel<<<1, 1024, 0, stream>>>(pair_out, out, npairs,
                                               1.0f / (float)npairs);
}

// Round 6
// 262.239 us; speedup vs baseline: 1.2381x; 1.2381x over previous
//
#include <hip/hip_runtime.h>

#define EPSF 1e-5f

typedef float f32x4 __attribute__((ext_vector_type(4)));

__device__ __forceinline__ f32x4 ntload(const f32x4* p) {
    return __builtin_nontemporal_load(p);
}

// Kernel 1: one WAVE (64 lanes) per (b,n) pair; 4 pairs per 256-thread block.
// 4+4 double-buffered non-temporal loads (deep MLP), 7 raw moments, wave
// shuffle reduce (no LDS/barriers), closed-form 2x2 cov/eig/loss on lane 0.
// Accumulation order identical to the round-3 kernel (bit-exact results).
__global__ __launch_bounds__(256) void star_pair_kernel(
    const float* __restrict__ heatmap,
    const float* __restrict__ gt,
    float* __restrict__ pair_out,
    int npairs)
{
    const int t = threadIdx.x;
    const int wave = t >> 6;
    const int lane = t & 63;
    const int pair = blockIdx.x * 4 + wave;
    if (pair >= npairs) return;

    const f32x4* hp4 = reinterpret_cast<const f32x4*>(heatmap + (size_t)pair * 4096);

    const float cgrid = 2.0f / 63.0f;
    // float4 index f = lane + 64*j -> x0 = (lane&15)*4 (const per thread),
    //                                  y  = (lane>>4) + 4*j
    const float xb = (float)((lane & 15) << 2);
    const float xf0 = fmaf(xb,        cgrid, -1.0f);
    const float xf1 = fmaf(xb + 1.0f, cgrid, -1.0f);
    const float xf2 = fmaf(xb + 2.0f, cgrid, -1.0f);
    const float xf3 = fmaf(xb + 3.0f, cgrid, -1.0f);
    const int   yb  = lane >> 4;

    float s0 = 0.f, s1 = 0.f, s2 = 0.f, s3 = 0.f, s4 = 0.f, s5 = 0.f, s6 = 0.f;

    f32x4 buf[2][4];

    // prologue: issue first 4 loads (j = 0..3)
    #pragma unroll
    for (int k = 0; k < 4; ++k)
        buf[0][k] = ntload(&hp4[lane + (k << 6)]);

    #pragma unroll
    for (int c = 0; c < 4; ++c) {
        // issue next chunk's 4 loads before consuming current chunk
        if (c < 3) {
            #pragma unroll
            for (int k = 0; k < 4; ++k)
                buf[(c + 1) & 1][k] = ntload(&hp4[lane + (((c + 1) * 4 + k) << 6)]);
        }
        // compute current chunk (j = c*4 + k), same order as before
        #pragma unroll
        for (int k = 0; k < 4; ++k) {
            const int j = c * 4 + k;
            const f32x4 v = buf[c & 1][k];
            const float yf = fmaf((float)(yb + (j << 2)), cgrid, -1.0f);
            const float a0 = v.x, a1 = v.y, a2 = v.z, a3 = v.w;

            s0 += a0; s6 = fmaf(a0, a0, s6);
            s1 = fmaf(a0, xf0, s1); s2 = fmaf(a0, yf, s2);
            { const float ax = a0 * xf0; s3 = fmaf(ax, xf0, s3); s4 = fmaf(ax, yf, s4); }
            { const float ay = a0 * yf;  s5 = fmaf(ay, yf, s5); }

            s0 += a1; s6 = fmaf(a1, a1, s6);
            s1 = fmaf(a1, xf1, s1); s2 = fmaf(a1, yf, s2);
            { const float ax = a1 * xf1; s3 = fmaf(ax, xf1, s3); s4 = fmaf(ax, yf, s4); }
            { const float ay = a1 * yf;  s5 = fmaf(ay, yf, s5); }

            s0 += a2; s6 = fmaf(a2, a2, s6);
            s1 = fmaf(a2, xf2, s1); s2 = fmaf(a2, yf, s2);
            { const float ax = a2 * xf2; s3 = fmaf(ax, xf2, s3); s4 = fmaf(ax, yf, s4); }
            { const float ay = a2 * yf;  s5 = fmaf(ay, yf, s5); }

            s0 += a3; s6 = fmaf(a3, a3, s6);
            s1 = fmaf(a3, xf3, s1); s2 = fmaf(a3, yf, s2);
            { const float ax = a3 * xf3; s3 = fmaf(ax, xf3, s3); s4 = fmaf(ax, yf, s4); }
            { const float ay = a3 * yf;  s5 = fmaf(ay, yf, s5); }
        }
    }

    // wave64 shuffle reduction, no LDS / no barrier
    #pragma unroll
    for (int off = 32; off >= 1; off >>= 1) {
        s0 += __shfl_down(s0, off);
        s1 += __shfl_down(s1, off);
        s2 += __shfl_down(s2, off);
        s3 += __shfl_down(s3, off);
        s4 += __shfl_down(s4, off);
        s5 += __shfl_down(s5, off);
        s6 += __shfl_down(s6, off);
    }

    if (lane == 0) {
        const float S = s0 > 1e-6f ? s0 : 1e-6f;
        const float inv = 1.0f / S;
        const float T  = s0 * inv;
        const float mx = s1 * inv;
        const float my = s2 * inv;
        const float Exx = s3 * inv;
        const float Exy = s4 * inv;
        const float Eyy = s5 * inv;
        const float V2raw = s6 * inv * inv;

        const float c2mT = 2.0f - T;
        float c00 = Exx - mx * mx * c2mT;
        float c01 = Exy - mx * my * c2mT;
        float c11 = Eyy - my * my * c2mT;
        const float V1 = T + EPSF;
        const float denom = V1 - (V2raw + EPSF) / V1;
        const float idn = 1.0f / denom;
        c00 *= idn; c01 *= idn; c11 *= idn;

        const float mmid = 0.5f * (c00 + c11);
        const float h = 0.5f * (c00 - c11);
        const float r = sqrtf(h * h + c01 * c01);
        const float l0 = mmid - r;
        const float l1 = mmid + r;
        float vx = h + r, vy = c01;
        const float nn = vx * vx + vy * vy;
        float cc, ssn;
        if (nn > 1e-30f) {
            const float rin = rsqrtf(nn);
            cc = vx * rin; ssn = vy * rin;
        } else {
            cc = 0.0f; ssn = 1.0f;
        }

        const float px = gt[2 * pair]     - mx;
        const float py = gt[2 * pair + 1] - my;
        const float r1 = cc * px + ssn * py;
        const float r0 = -ssn * px + cc * py;

        const float ssum = r0 * r0 / (l0 + EPSF) + r1 * r1 / (l1 + EPSF);
        const float esum = fabsf(l0) + fabsf(l1);
        pair_out[pair] = 0.5f * ssum + esum;
    }
}

// Kernel 2: reduce per-pair contributions -> scalar loss.
__global__ __launch_bounds__(1024) void star_reduce_kernel(
    const float* __restrict__ pair_out,
    float* __restrict__ out,
    int n, float inv_n)
{
    float s = 0.f;
    for (int i = threadIdx.x; i < n; i += 1024) s += pair_out[i];
    #pragma unroll
    for (int off = 32; off >= 1; off >>= 1) s += __shfl_down(s, off);
    __shared__ float red[16];
    const int wave = threadIdx.x >> 6;
    const int lane = threadIdx.x & 63;
    if (lane == 0) red[wave] = s;
    __syncthreads();
    if (threadIdx.x == 0) {
        float tot = 0.f;
        #pragma unroll
        for (int w = 0; w < 16; ++w) tot += red[w];
        out[0] = tot * inv_n;
    }
}

extern "C" void kernel_launch(void* const* d_in, const int* in_sizes, int n_in,
                              void* d_out, int out_size, void* d_ws, size_t ws_size,
                              hipStream_t stream) {
    const float* heatmap = (const float*)d_in[0];
    const float* gt      = (const float*)d_in[1];
    float* out = (float*)d_out;
    float* pair_out = (float*)d_ws;

    const int npairs = in_sizes[1] / 2;   // 128*98 = 12544
    const int nblocks = (npairs + 3) / 4; // 4 pairs (waves) per block

    star_pair_kernel<<<nblocks, 256, 0, stream>>>(heatmap, gt, pair_out, npairs);
    star_reduce_kernel<<<1, 1024, 0, stream>>>(pair_out, out, npairs,
                                               1.0f / (float)npairs);
}